// Round 9
// baseline (196.970 us; speedup 1.0000x reference)
//
#include <hip/hip_runtime.h>
#include <hip/hip_bf16.h>
#include <stdint.h>

#define N_NODES 4096
#define BATCH 2
#define AGG_GRID 1024

typedef __attribute__((ext_vector_type(8))) short short8v;
typedef __attribute__((ext_vector_type(4))) unsigned short ushort4v;
typedef __attribute__((ext_vector_type(4))) float f32x4;

#define GLL16(gsrc, ldst) \
    __builtin_amdgcn_global_load_lds((const __attribute__((address_space(1))) void*)(gsrc), \
                                     (__attribute__((address_space(3))) void*)(ldst), 16, 0, 0)

static __device__ inline unsigned short f2bf_rn(float x) {
    unsigned u = __float_as_uint(x);
    unsigned r = (u + 0x7FFFu + ((u >> 16) & 1u)) >> 16;
    return (unsigned short)r;
}
static __device__ inline float bf2f(unsigned short b) {
    return __uint_as_float(((unsigned)b) << 16);
}
static __device__ inline float rl(float v, int k) {   // wave-uniform broadcast
    return __uint_as_float(__builtin_amdgcn_readlane(__float_as_uint(v), k));
}

// Software grid barrier (R8-proven coherence pattern). Counter zeroed by
// hipMemsetAsync at the top of every kernel_launch (capture-safe).
static __device__ inline void grid_bar(unsigned* ctr, unsigned target) {
    __syncthreads();
    if (threadIdx.x == 0) {
        __threadfence();                                  // device release
        atomicAdd(ctr, 1u);                               // device scope
        while (__hip_atomic_load(ctr, __ATOMIC_ACQUIRE,
                                 __HIP_MEMORY_SCOPE_AGENT) < target)
            __builtin_amdgcn_s_sleep(8);
    }
    __syncthreads();
}

// ---------------------------------------------------------------------------
// K1 (R4-verified): blocks [0,256) norm -> split-bf16; [256,512) feat1.
// ---------------------------------------------------------------------------
__global__ __launch_bounds__(256) void k1_kernel(
        const float* __restrict__ emb,
        unsigned short* __restrict__ ne_hi, unsigned short* __restrict__ ne_lo,
        const float* __restrict__ x, const float* __restrict__ Wp,
        const float* __restrict__ bp, const float* __restrict__ W1,
        const float* __restrict__ a1s, const float* __restrict__ a1d,
        float* __restrict__ h1out, float* __restrict__ ssrc, float* __restrict__ sdst) {
    int t = threadIdx.x;
    if (blockIdx.x < 256) {
        int row = blockIdx.x * 16 + (t >> 4);
        int l16 = t & 15;
        float4 v = *(const float4*)&emb[(size_t)row * 64 + l16 * 4];
        float s = v.x * v.x + v.y * v.y + v.z * v.z + v.w * v.w;
#pragma unroll
        for (int m = 8; m >= 1; m >>= 1) s += __shfl_xor(s, m);
        float inv = 1.f / sqrtf(s);
        float n0 = v.x * inv, n1 = v.y * inv, n2 = v.z * inv, n3 = v.w * inv;
        ushort4v h = {f2bf_rn(n0), f2bf_rn(n1), f2bf_rn(n2), f2bf_rn(n3)};
        ushort4v lo = {f2bf_rn(n0 - bf2f(h.x)), f2bf_rn(n1 - bf2f(h.y)),
                       f2bf_rn(n2 - bf2f(h.z)), f2bf_rn(n3 - bf2f(h.w))};
        *(ushort4v*)&ne_hi[(size_t)row * 64 + l16 * 4] = h;
        *(ushort4v*)&ne_lo[(size_t)row * 64 + l16 * 4] = lo;
    } else {
        int b = blockIdx.x - 256;
        int w = t >> 6, l = t & 63;
        int row0 = b * 32 + w * 8;

        float xv[8];
#pragma unroll
        for (int r = 0; r < 8; ++r) xv[r] = x[(size_t)(row0 + r) * 16 + (l & 15)];

        float h0[8];
        float bpv = bp[l];
#pragma unroll
        for (int r = 0; r < 8; ++r) h0[r] = bpv;
#pragma unroll
        for (int k = 0; k < 16; ++k) {
            float wk = Wp[k * 64 + l];
#pragma unroll
            for (int r = 0; r < 8; ++r) h0[r] += rl(xv[r], k) * wk;
        }

        float h1[8] = {0.f, 0.f, 0.f, 0.f, 0.f, 0.f, 0.f, 0.f};
#pragma unroll
        for (int k = 0; k < 64; ++k) {
            float wk = W1[k * 64 + l];
#pragma unroll
            for (int r = 0; r < 8; ++r) h1[r] += rl(h0[r], k) * wk;
        }

        float as_ = a1s[l], ad_ = a1d[l];
#pragma unroll
        for (int r = 0; r < 8; ++r) {
            h1out[(size_t)(row0 + r) * 64 + l] = h1[r];
            float ps = h1[r] * as_, pd = h1[r] * ad_;
#pragma unroll
            for (int m = 8; m >= 1; m >>= 1) {
                ps += __shfl_xor(ps, m);
                pd += __shfl_xor(pd, m);
            }
            if ((l & 15) == 0) {
                ssrc[(size_t)(row0 + r) * 4 + (l >> 4)] = ps;
                sdst[(size_t)(row0 + r) * 4 + (l >> 4)] = pd;
            }
        }
    }
}

// ---------------------------------------------------------------------------
// K2 (R4-verified): adjacency bitmask, 128x128 tile/block, LDS-staged MFMA.
// ---------------------------------------------------------------------------
__global__ __launch_bounds__(256) void adj_mfma_kernel(
        const unsigned short* __restrict__ hi, const unsigned short* __restrict__ lo,
        unsigned long long* __restrict__ mask) {
    __shared__ unsigned short Ah[128 * 64];
    __shared__ unsigned short Al[128 * 64];
    __shared__ unsigned short Bh[128 * 64];
    __shared__ unsigned short Bl[128 * 64];
    int t = threadIdx.x;
    int w = t >> 6, l = t & 63;
    int i0 = blockIdx.y * 128, j0 = blockIdx.x * 128;

    int cr = l >> 3;
    int slot = (l & 7) ^ cr;
#pragma unroll
    for (int q = 0; q < 4; ++q) {
        int lr = w * 32 + q * 8;
        size_t ga = (size_t)(i0 + lr + cr) * 64 + slot * 8;
        size_t gb = (size_t)(j0 + lr + cr) * 64 + slot * 8;
        GLL16(hi + ga, &Ah[lr * 64]);
        GLL16(lo + ga, &Al[lr * 64]);
        GLL16(hi + gb, &Bh[lr * 64]);
        GLL16(lo + gb, &Bl[lr * 64]);
    }
    __syncthreads();

    int fr = l & 15;
    int s0 = l >> 4;
    int r7 = l & 7;
    short8v aH[2][2], aL[2][2];
#pragma unroll
    for (int rt = 0; rt < 2; ++rt) {
        int base = (w * 32 + rt * 16 + fr) * 64;
        aH[rt][0] = *(const short8v*)&Ah[base + ((s0 ^ r7) << 3)];
        aH[rt][1] = *(const short8v*)&Ah[base + (((s0 + 4) ^ r7) << 3)];
        aL[rt][0] = *(const short8v*)&Al[base + ((s0 ^ r7) << 3)];
        aL[rt][1] = *(const short8v*)&Al[base + (((s0 + 4) ^ r7) << 3)];
    }

    f32x4 acc[2][8];
#pragma unroll
    for (int rt = 0; rt < 2; ++rt)
#pragma unroll
        for (int js = 0; js < 8; ++js) acc[rt][js] = (f32x4){0.f, 0.f, 0.f, 0.f};

#pragma unroll
    for (int js = 0; js < 8; ++js) {
        int bbase = (js * 16 + fr) * 64;
        short8v bH0 = *(const short8v*)&Bh[bbase + ((s0 ^ r7) << 3)];
        short8v bH1 = *(const short8v*)&Bh[bbase + (((s0 + 4) ^ r7) << 3)];
        short8v bL0 = *(const short8v*)&Bl[bbase + ((s0 ^ r7) << 3)];
        short8v bL1 = *(const short8v*)&Bl[bbase + (((s0 + 4) ^ r7) << 3)];
#pragma unroll
        for (int rt = 0; rt < 2; ++rt) {
            f32x4 a = acc[rt][js];
            a = __builtin_amdgcn_mfma_f32_16x16x32_bf16(aH[rt][0], bH0, a, 0, 0, 0);
            a = __builtin_amdgcn_mfma_f32_16x16x32_bf16(aH[rt][1], bH1, a, 0, 0, 0);
            a = __builtin_amdgcn_mfma_f32_16x16x32_bf16(aH[rt][0], bL0, a, 0, 0, 0);
            a = __builtin_amdgcn_mfma_f32_16x16x32_bf16(aH[rt][1], bL1, a, 0, 0, 0);
            a = __builtin_amdgcn_mfma_f32_16x16x32_bf16(aL[rt][0], bH0, a, 0, 0, 0);
            a = __builtin_amdgcn_mfma_f32_16x16x32_bf16(aL[rt][1], bH1, a, 0, 0, 0);
            acc[rt][js] = a;
        }
    }

    int shift = ((l & 15) >> 2) * 16;
    int r = l & 3;
#pragma unroll
    for (int rt = 0; rt < 2; ++rt) {
#pragma unroll
        for (int ws_ = 0; ws_ < 2; ++ws_) {
            unsigned long long w64 = 0;
#pragma unroll
            for (int js2 = 0; js2 < 4; ++js2) {
                f32x4 a = acc[rt][ws_ * 4 + js2];
                unsigned long long c0 = __ballot(a[0] > 0.5f);
                unsigned long long c1 = __ballot(a[1] > 0.5f);
                unsigned long long c2 = __ballot(a[2] > 0.5f);
                unsigned long long c3 = __ballot(a[3] > 0.5f);
                unsigned long long sel = r == 0 ? c0 : r == 1 ? c1 : r == 2 ? c2 : c3;
                w64 |= ((sel >> shift) & 0xFFFFULL) << (js2 * 16);
            }
            if (l < 16)
                mask[(size_t)(i0 + w * 32 + rt * 16 + l) * 64 + blockIdx.x * 2 + ws_] = w64;
        }
    }
}

// ---------------------------------------------------------------------------
// K3: merged agg1(+bias+ReLU)+mm2+scores2  -> grid_bar ->  agg2 -> out.
// No LDS; grid 1024 = 4 blocks/CU (capacity 8 at launch_bounds(256,4) -> safe
// co-residency margin 2x). Each phase: 2 units/block, 1 row/wave per unit.
// ---------------------------------------------------------------------------
struct AggParams {
    const float* h1;
    const float* s1s;
    const float* s1d;
    const unsigned long long* mask;
    const float* b1;
    const float* W2;
    const float* a2s;
    const float* a2d;
    const float* b2;
    float* h2;
    float* s2s;
    float* s2d;
    float* out;
    unsigned* bar;
};

__global__ __launch_bounds__(256, 4) void agg_kernel(AggParams p) {
    int t = threadIdx.x;
    int bid = blockIdx.x;
    int w = t >> 6, l = t & 63;

    // ===== Phase C: agg1 + mm2 + scores2 =====
    {
        int hh = l >> 4;
        int l2 = l & 31;
#pragma unroll 1
        for (int u = bid; u < 2048; u += AGG_GRID) {
            int row = u * 4 + w;
            int i = row & (N_NODES - 1);
            int bN = row - i;

            float sd = p.s1d[(size_t)row * 4 + hh];
            unsigned long long myword = p.mask[(size_t)i * 64 + l];

            float m = -1e30f, denom = 0.f, acc = 0.f;
            unsigned long long nz = __ballot(myword != 0ULL);
            while (nz) {
                int lw = __ffsll(nz) - 1;
                nz &= nz - 1;
                unsigned long long wbits = __shfl(myword, lw);
                while (wbits) {
                    int bpos = __ffsll(wbits) - 1;
                    wbits &= wbits - 1;
                    int j = (lw << 6) + bpos;
                    float e = sd + p.s1s[(size_t)(bN + j) * 4 + hh];
                    e = e > 0.f ? e : 0.2f * e;
                    float mn = fmaxf(m, e);
                    float cf = __expf(m - mn);
                    float wg = __expf(e - mn);
                    float hv = p.h1[(size_t)(bN + j) * 64 + l];
                    denom = denom * cf + wg;
                    acc = acc * cf + wg * hv;
                    m = mn;
                }
            }
            float o = fmaxf(acc / denom + p.b1[l], 0.f);

            float acc2 = 0.f;
#pragma unroll
            for (int k = 0; k < 64; ++k) acc2 += rl(o, k) * p.W2[k * 32 + l2];

            float ps = acc2 * p.a2s[l2], pd = acc2 * p.a2d[l2];
#pragma unroll
            for (int mm = 4; mm >= 1; mm >>= 1) {
                ps += __shfl_xor(ps, mm);
                pd += __shfl_xor(pd, mm);
            }
            if (l < 32) {
                p.h2[(size_t)row * 32 + l] = acc2;
                if ((l & 7) == 0) {
                    p.s2s[(size_t)row * 4 + (l >> 3)] = ps;
                    p.s2d[(size_t)row * 4 + (l >> 3)] = pd;
                }
            }
        }
    }

    grid_bar(p.bar, AGG_GRID);

    // ===== Phase D: agg2 -> out =====
    {
        int tt = l & 31;
        int hh = tt >> 3;
#pragma unroll 1
        for (int u = bid; u < 2048; u += AGG_GRID) {
            int row = u * 4 + w;
            int i = row & (N_NODES - 1);
            int bN = row - i;

            float sd = p.s2d[(size_t)row * 4 + hh];
            unsigned long long myword = p.mask[(size_t)i * 64 + l];

            float m = -1e30f, denom = 0.f, acc = 0.f;
            unsigned long long nz = __ballot(myword != 0ULL);
            while (nz) {
                int lw = __ffsll(nz) - 1;
                nz &= nz - 1;
                unsigned long long wbits = __shfl(myword, lw);
                while (wbits) {
                    int bpos = __ffsll(wbits) - 1;
                    wbits &= wbits - 1;
                    int j = (lw << 6) + bpos;
                    float e = sd + p.s2s[(size_t)(bN + j) * 4 + hh];
                    e = e > 0.f ? e : 0.2f * e;
                    float mn = fmaxf(m, e);
                    float cf = __expf(m - mn);
                    float wg = __expf(e - mn);
                    float hv = p.h2[(size_t)(bN + j) * 32 + tt];
                    denom = denom * cf + wg;
                    acc = acc * cf + wg * hv;
                    m = mn;
                }
            }
            float o = acc / denom + p.b2[tt];
            if (l < 32) p.out[(size_t)row * 32 + tt] = o;
        }
    }
}

// ---------------------------------------------------------------------------
extern "C" void kernel_launch(void* const* d_in, const int* in_sizes, int n_in,
                              void* d_out, int out_size, void* d_ws, size_t ws_size,
                              hipStream_t stream) {
    const float* x   = (const float*)d_in[0];
    const float* emb = (const float*)d_in[1];
    const float* Wp  = (const float*)d_in[2];
    const float* bp  = (const float*)d_in[3];
    const float* W1  = (const float*)d_in[4];
    const float* a1s = (const float*)d_in[5];
    const float* a1d = (const float*)d_in[6];
    const float* b1  = (const float*)d_in[7];
    const float* W2  = (const float*)d_in[8];
    const float* a2s = (const float*)d_in[9];
    const float* a2d = (const float*)d_in[10];
    const float* b2  = (const float*)d_in[11];

    const int ROWS = BATCH * N_NODES;  // 8192

    char* w = (char*)d_ws;
    unsigned short* ne_hi = (unsigned short*)w;  w += (size_t)N_NODES * 64 * 2;
    unsigned short* ne_lo = (unsigned short*)w;  w += (size_t)N_NODES * 64 * 2;
    unsigned long long* mask = (unsigned long long*)w; w += (size_t)N_NODES * 64 * 8;
    float* h1  = (float*)w;                      w += (size_t)ROWS * 64 * 4;
    float* s1s = (float*)w;                      w += (size_t)ROWS * 4 * 4;
    float* s1d = (float*)w;                      w += (size_t)ROWS * 4 * 4;
    float* h2  = (float*)w;                      w += (size_t)ROWS * 32 * 4;
    float* s2s = (float*)w;                      w += (size_t)ROWS * 4 * 4;
    float* s2d = (float*)w;                      w += (size_t)ROWS * 4 * 4;
    unsigned* bar = (unsigned*)w;                w += 64;

    AggParams p;
    p.h1 = h1;
    p.s1s = s1s;
    p.s1d = s1d;
    p.mask = mask;
    p.b1 = b1;
    p.W2 = W2;
    p.a2s = a2s;
    p.a2d = a2d;
    p.b2 = b2;
    p.h2 = h2;
    p.s2s = s2s;
    p.s2d = s2d;
    p.out = (float*)d_out;
    p.bar = bar;

    hipMemsetAsync(bar, 0, 64, stream);
    k1_kernel<<<dim3(512), dim3(256), 0, stream>>>(
        emb, ne_hi, ne_lo, x, Wp, bp, W1, a1s, a1d, h1, s1s, s1d);
    adj_mfma_kernel<<<dim3(32, 32), dim3(256), 0, stream>>>(ne_hi, ne_lo, mask);
    agg_kernel<<<dim3(AGG_GRID), dim3(256), 0, stream>>>(p);
}

// Round 10
// 40.043 us; speedup vs baseline: 4.9190x; 4.9190x over previous
//
#include <hip/hip_runtime.h>
#include <hip/hip_bf16.h>
#include <stdint.h>

#define N_NODES 4096
#define BATCH 2
#define EL_CAP 16

typedef __attribute__((ext_vector_type(8))) short short8v;
typedef __attribute__((ext_vector_type(4))) unsigned short ushort4v;
typedef __attribute__((ext_vector_type(4))) float f32x4;

#define GLL16(gsrc, ldst) \
    __builtin_amdgcn_global_load_lds((const __attribute__((address_space(1))) void*)(gsrc), \
                                     (__attribute__((address_space(3))) void*)(ldst), 16, 0, 0)

static __device__ inline unsigned short f2bf_rn(float x) {
    unsigned u = __float_as_uint(x);
    unsigned r = (u + 0x7FFFu + ((u >> 16) & 1u)) >> 16;
    return (unsigned short)r;
}
static __device__ inline float bf2f(unsigned short b) {
    return __uint_as_float(((unsigned)b) << 16);
}
static __device__ inline float rl(float v, int k) {   // wave-uniform broadcast
    return __uint_as_float(__builtin_amdgcn_readlane(__float_as_uint(v), k));
}

// ---------------------------------------------------------------------------
// K1 (R4-verified): blocks [0,256) norm -> split-bf16; [256,512) feat1.
// ---------------------------------------------------------------------------
__global__ __launch_bounds__(256) void k1_kernel(
        const float* __restrict__ emb,
        unsigned short* __restrict__ ne_hi, unsigned short* __restrict__ ne_lo,
        const float* __restrict__ x, const float* __restrict__ Wp,
        const float* __restrict__ bp, const float* __restrict__ W1,
        const float* __restrict__ a1s, const float* __restrict__ a1d,
        float* __restrict__ h1out, float* __restrict__ ssrc, float* __restrict__ sdst) {
    int t = threadIdx.x;
    if (blockIdx.x < 256) {
        int row = blockIdx.x * 16 + (t >> 4);
        int l16 = t & 15;
        float4 v = *(const float4*)&emb[(size_t)row * 64 + l16 * 4];
        float s = v.x * v.x + v.y * v.y + v.z * v.z + v.w * v.w;
#pragma unroll
        for (int m = 8; m >= 1; m >>= 1) s += __shfl_xor(s, m);
        float inv = 1.f / sqrtf(s);
        float n0 = v.x * inv, n1 = v.y * inv, n2 = v.z * inv, n3 = v.w * inv;
        ushort4v h = {f2bf_rn(n0), f2bf_rn(n1), f2bf_rn(n2), f2bf_rn(n3)};
        ushort4v lo = {f2bf_rn(n0 - bf2f(h.x)), f2bf_rn(n1 - bf2f(h.y)),
                       f2bf_rn(n2 - bf2f(h.z)), f2bf_rn(n3 - bf2f(h.w))};
        *(ushort4v*)&ne_hi[(size_t)row * 64 + l16 * 4] = h;
        *(ushort4v*)&ne_lo[(size_t)row * 64 + l16 * 4] = lo;
    } else {
        int b = blockIdx.x - 256;
        int w = t >> 6, l = t & 63;
        int row0 = b * 32 + w * 8;

        float xv[8];
#pragma unroll
        for (int r = 0; r < 8; ++r) xv[r] = x[(size_t)(row0 + r) * 16 + (l & 15)];

        float h0[8];
        float bpv = bp[l];
#pragma unroll
        for (int r = 0; r < 8; ++r) h0[r] = bpv;
#pragma unroll
        for (int k = 0; k < 16; ++k) {
            float wk = Wp[k * 64 + l];
#pragma unroll
            for (int r = 0; r < 8; ++r) h0[r] += rl(xv[r], k) * wk;
        }

        float h1[8] = {0.f, 0.f, 0.f, 0.f, 0.f, 0.f, 0.f, 0.f};
#pragma unroll
        for (int k = 0; k < 64; ++k) {
            float wk = W1[k * 64 + l];
#pragma unroll
            for (int r = 0; r < 8; ++r) h1[r] += rl(h0[r], k) * wk;
        }

        float as_ = a1s[l], ad_ = a1d[l];
#pragma unroll
        for (int r = 0; r < 8; ++r) {
            h1out[(size_t)(row0 + r) * 64 + l] = h1[r];
            float ps = h1[r] * as_, pd = h1[r] * ad_;
#pragma unroll
            for (int m = 8; m >= 1; m >>= 1) {
                ps += __shfl_xor(ps, m);
                pd += __shfl_xor(pd, m);
            }
            if ((l & 15) == 0) {
                ssrc[(size_t)(row0 + r) * 4 + (l >> 4)] = ps;
                sdst[(size_t)(row0 + r) * 4 + (l >> 4)] = pd;
            }
        }
    }
}

// ---------------------------------------------------------------------------
// K2: adjacency bitmask, UPPER-TRIANGLE tiles only (bj >= bi); each off-diag
// tile also stores its bit-transposed mirror. 128x128 tile/block, LDS-staged
// split-bf16 MFMA (R4-verified core).
// ---------------------------------------------------------------------------
__global__ __launch_bounds__(256) void adj_mfma_kernel(
        const unsigned short* __restrict__ hi, const unsigned short* __restrict__ lo,
        unsigned long long* __restrict__ mask) {
    __shared__ unsigned short Ah[128 * 64];
    __shared__ unsigned short Al[128 * 64];
    __shared__ unsigned short Bh[128 * 64];
    __shared__ unsigned short Bl[128 * 64];
    int bi = blockIdx.y, bj = blockIdx.x;
    if (bj < bi) return;                       // symmetric: skip lower triangle
    int t = threadIdx.x;
    int w = t >> 6, l = t & 63;
    int i0 = bi * 128, j0 = bj * 128;

    int cr = l >> 3;
    int slot = (l & 7) ^ cr;
#pragma unroll
    for (int q = 0; q < 4; ++q) {
        int lr = w * 32 + q * 8;
        size_t ga = (size_t)(i0 + lr + cr) * 64 + slot * 8;
        size_t gb = (size_t)(j0 + lr + cr) * 64 + slot * 8;
        GLL16(hi + ga, &Ah[lr * 64]);
        GLL16(lo + ga, &Al[lr * 64]);
        GLL16(hi + gb, &Bh[lr * 64]);
        GLL16(lo + gb, &Bl[lr * 64]);
    }
    __syncthreads();

    int fr = l & 15;
    int s0 = l >> 4;
    int r7 = l & 7;
    short8v aH[2][2], aL[2][2];
#pragma unroll
    for (int rt = 0; rt < 2; ++rt) {
        int base = (w * 32 + rt * 16 + fr) * 64;
        aH[rt][0] = *(const short8v*)&Ah[base + ((s0 ^ r7) << 3)];
        aH[rt][1] = *(const short8v*)&Ah[base + (((s0 + 4) ^ r7) << 3)];
        aL[rt][0] = *(const short8v*)&Al[base + ((s0 ^ r7) << 3)];
        aL[rt][1] = *(const short8v*)&Al[base + (((s0 + 4) ^ r7) << 3)];
    }

    f32x4 acc[2][8];
#pragma unroll
    for (int rt = 0; rt < 2; ++rt)
#pragma unroll
        for (int js = 0; js < 8; ++js) acc[rt][js] = (f32x4){0.f, 0.f, 0.f, 0.f};

#pragma unroll
    for (int js = 0; js < 8; ++js) {
        int bbase = (js * 16 + fr) * 64;
        short8v bH0 = *(const short8v*)&Bh[bbase + ((s0 ^ r7) << 3)];
        short8v bH1 = *(const short8v*)&Bh[bbase + (((s0 + 4) ^ r7) << 3)];
        short8v bL0 = *(const short8v*)&Bl[bbase + ((s0 ^ r7) << 3)];
        short8v bL1 = *(const short8v*)&Bl[bbase + (((s0 + 4) ^ r7) << 3)];
#pragma unroll
        for (int rt = 0; rt < 2; ++rt) {
            f32x4 a = acc[rt][js];
            a = __builtin_amdgcn_mfma_f32_16x16x32_bf16(aH[rt][0], bH0, a, 0, 0, 0);
            a = __builtin_amdgcn_mfma_f32_16x16x32_bf16(aH[rt][1], bH1, a, 0, 0, 0);
            a = __builtin_amdgcn_mfma_f32_16x16x32_bf16(aH[rt][0], bL0, a, 0, 0, 0);
            a = __builtin_amdgcn_mfma_f32_16x16x32_bf16(aH[rt][1], bL1, a, 0, 0, 0);
            a = __builtin_amdgcn_mfma_f32_16x16x32_bf16(aL[rt][0], bH0, a, 0, 0, 0);
            a = __builtin_amdgcn_mfma_f32_16x16x32_bf16(aL[rt][1], bH1, a, 0, 0, 0);
            acc[rt][js] = a;
        }
    }

    // all LDS reads done; Ah space is reused below as transpose staging
    __syncthreads();
    unsigned char* ldsT = (unsigned char*)Ah;    // [128 cols][4 waves][4 bytes]
    unsigned* ldsT32 = (unsigned*)Ah;

    int c16 = l & 15;
    int q = l >> 4;                 // 0..3 -> (rt = q>>1, rg-pair = q&1)
    int trt = q >> 1;
    int rgb = (q & 1) * 2;
    unsigned sh0 = c16 + 16 * rgb, sh1 = c16 + 16 * (rgb + 1);

    int shift = (c16 >> 2) * 16;
    int r = l & 3;
#pragma unroll
    for (int ws_ = 0; ws_ < 2; ++ws_) {
        unsigned long long w64_0 = 0, w64_1 = 0;
#pragma unroll
        for (int js2 = 0; js2 < 4; ++js2) {
            int js = ws_ * 4 + js2;
            f32x4 a0 = acc[0][js], a1 = acc[1][js];
            unsigned long long B00 = __ballot(a0[0] > 0.5f);
            unsigned long long B01 = __ballot(a0[1] > 0.5f);
            unsigned long long B02 = __ballot(a0[2] > 0.5f);
            unsigned long long B03 = __ballot(a0[3] > 0.5f);
            unsigned long long B10 = __ballot(a1[0] > 0.5f);
            unsigned long long B11 = __ballot(a1[1] > 0.5f);
            unsigned long long B12 = __ballot(a1[2] > 0.5f);
            unsigned long long B13 = __ballot(a1[3] > 0.5f);

            // normal pack (rows of i-panel)
            unsigned long long sel0 = r == 0 ? B00 : r == 1 ? B01 : r == 2 ? B02 : B03;
            unsigned long long sel1 = r == 0 ? B10 : r == 1 ? B11 : r == 2 ? B12 : B13;
            w64_0 |= ((sel0 >> shift) & 0xFFFFULL) << (js2 * 16);
            w64_1 |= ((sel1 >> shift) & 0xFFFFULL) << (js2 * 16);

            // transpose partial: lane (c16 + 16q) -> byte q of column js*16+c16
            if (bi != bj) {
                unsigned long long s0_ = trt ? B10 : B00;
                unsigned long long s1_ = trt ? B11 : B01;
                unsigned long long s2_ = trt ? B12 : B02;
                unsigned long long s3_ = trt ? B13 : B03;
                unsigned p8 =
                    ((unsigned)(s0_ >> sh0) & 1u) |
                    (((unsigned)(s1_ >> sh0) & 1u) << 1) |
                    (((unsigned)(s2_ >> sh0) & 1u) << 2) |
                    (((unsigned)(s3_ >> sh0) & 1u) << 3) |
                    (((unsigned)(s0_ >> sh1) & 1u) << 4) |
                    (((unsigned)(s1_ >> sh1) & 1u) << 5) |
                    (((unsigned)(s2_ >> sh1) & 1u) << 6) |
                    (((unsigned)(s3_ >> sh1) & 1u) << 7);
                ldsT[(js * 16 + c16) * 16 + w * 4 + q] = (unsigned char)p8;
            }
        }
        if (l < 16) {
            mask[(size_t)(i0 + w * 32 + 0 * 16 + l) * 64 + bj * 2 + ws_] = w64_0;
            mask[(size_t)(i0 + w * 32 + 1 * 16 + l) * 64 + bj * 2 + ws_] = w64_1;
        }
    }

    if (bi != bj) {
        __syncthreads();
        if (t < 128) {
            unsigned u0 = ldsT32[t * 4 + 0];
            unsigned u1 = ldsT32[t * 4 + 1];
            unsigned u2 = ldsT32[t * 4 + 2];
            unsigned u3 = ldsT32[t * 4 + 3];
            unsigned long long word0 = (unsigned long long)u0 | ((unsigned long long)u1 << 32);
            unsigned long long word1 = (unsigned long long)u2 | ((unsigned long long)u3 << 32);
            mask[(size_t)(j0 + t) * 64 + bi * 2 + 0] = word0;
            mask[(size_t)(j0 + t) * 64 + bi * 2 + 1] = word1;
        }
    }
}

// ---------------------------------------------------------------------------
// K3: agg1(+bias+ReLU)+mm2+scores2; also emits compact edge list per node.
// 4 rows/block, wave/row (R4-verified structure).
// ---------------------------------------------------------------------------
__global__ __launch_bounds__(256) void agg1_fused_kernel(
        const float* __restrict__ h1, const float* __restrict__ ssrc,
        const float* __restrict__ sdst, const unsigned long long* __restrict__ mask,
        const float* __restrict__ b1, const float* __restrict__ W2,
        const float* __restrict__ a2s, const float* __restrict__ a2d,
        float* __restrict__ h2out, float* __restrict__ s2s, float* __restrict__ s2d,
        int* __restrict__ ecnt, int* __restrict__ elist) {
    int row = blockIdx.x * 4 + (threadIdx.x >> 6);
    int i = row & (N_NODES - 1);
    int bN = row - i;
    int t = threadIdx.x & 63;
    int hh = t >> 4;

    float sd = sdst[(size_t)row * 4 + hh];
    unsigned long long myword = mask[(size_t)i * 64 + t];
    bool emit = (row < N_NODES);    // batch 0 builds the shared edge list
    int cnt = 0;

    float m = -1e30f, denom = 0.f, acc = 0.f;
    unsigned long long nz = __ballot(myword != 0ULL);
    while (nz) {
        int lw = __ffsll(nz) - 1;
        nz &= nz - 1;
        unsigned long long wbits = __shfl(myword, lw);
        while (wbits) {
            int bpos = __ffsll(wbits) - 1;
            wbits &= wbits - 1;
            int j = (lw << 6) + bpos;
            if (emit) {
                if (t == 0 && cnt < EL_CAP) elist[(size_t)i * EL_CAP + cnt] = j;
                ++cnt;
            }
            float e = sd + ssrc[(size_t)(bN + j) * 4 + hh];
            e = e > 0.f ? e : 0.2f * e;
            float mn = fmaxf(m, e);
            float cf = __expf(m - mn);
            float wg = __expf(e - mn);
            float hv = h1[(size_t)(bN + j) * 64 + t];
            denom = denom * cf + wg;
            acc = acc * cf + wg * hv;
            m = mn;
        }
    }
    if (emit && t == 0) ecnt[i] = cnt;

    float o = fmaxf(acc / denom + b1[t], 0.f);   // out1 row, lane t = feature t

    // mm2: h2[t'] = sum_k o_k * W2[k*32+t']  (lanes 32..63 duplicate 0..31)
    int l2 = t & 31;
    float acc2 = 0.f;
#pragma unroll
    for (int k = 0; k < 64; ++k) acc2 += rl(o, k) * W2[k * 32 + l2];

    float ps = acc2 * a2s[l2], pd = acc2 * a2d[l2];
#pragma unroll
    for (int mm = 4; mm >= 1; mm >>= 1) {
        ps += __shfl_xor(ps, mm);
        pd += __shfl_xor(pd, mm);
    }
    if (t < 32) {
        h2out[(size_t)row * 32 + t] = acc2;
        if ((t & 7) == 0) {
            s2s[(size_t)row * 4 + (t >> 3)] = ps;
            s2d[(size_t)row * 4 + (t >> 3)] = pd;
        }
    }
}

// ---------------------------------------------------------------------------
// K4: agg2 via compact edge list (fallback: mask scan). 4 rows/block.
// ---------------------------------------------------------------------------
__global__ __launch_bounds__(256) void agg2_kernel(
        const float* __restrict__ hfeat, const float* __restrict__ ssrc,
        const float* __restrict__ sdst, const unsigned long long* __restrict__ mask,
        const float* __restrict__ bias, const int* __restrict__ ecnt,
        const int* __restrict__ elist, float* __restrict__ out) {
    int row = blockIdx.x * 4 + (threadIdx.x >> 6);
    int i = row & (N_NODES - 1);
    int bN = row - i;
    int t = threadIdx.x & 63;
    int tt = t & 31;
    int hh = tt >> 3;

    float sd = sdst[(size_t)row * 4 + hh];
    int cnt = ecnt[i];

    float m = -1e30f, denom = 0.f, acc = 0.f;
    if (cnt <= EL_CAP) {
#pragma unroll 1
        for (int k = 0; k < cnt; ++k) {
            int j = elist[(size_t)i * EL_CAP + k];
            float e = sd + ssrc[(size_t)(bN + j) * 4 + hh];
            e = e > 0.f ? e : 0.2f * e;
            float mn = fmaxf(m, e);
            float cf = __expf(m - mn);
            float wg = __expf(e - mn);
            float hv = hfeat[(size_t)(bN + j) * 32 + tt];
            denom = denom * cf + wg;
            acc = acc * cf + wg * hv;
            m = mn;
        }
    } else {
        unsigned long long myword = mask[(size_t)i * 64 + t];
        unsigned long long nz = __ballot(myword != 0ULL);
        while (nz) {
            int lw = __ffsll(nz) - 1;
            nz &= nz - 1;
            unsigned long long wbits = __shfl(myword, lw);
            while (wbits) {
                int bpos = __ffsll(wbits) - 1;
                wbits &= wbits - 1;
                int j = (lw << 6) + bpos;
                float e = sd + ssrc[(size_t)(bN + j) * 4 + hh];
                e = e > 0.f ? e : 0.2f * e;
                float mn = fmaxf(m, e);
                float cf = __expf(m - mn);
                float wg = __expf(e - mn);
                float hv = hfeat[(size_t)(bN + j) * 32 + tt];
                denom = denom * cf + wg;
                acc = acc * cf + wg * hv;
                m = mn;
            }
        }
    }
    float o = acc / denom + bias[tt];
    if (t < 32) out[(size_t)row * 32 + tt] = o;
}

// ---------------------------------------------------------------------------
extern "C" void kernel_launch(void* const* d_in, const int* in_sizes, int n_in,
                              void* d_out, int out_size, void* d_ws, size_t ws_size,
                              hipStream_t stream) {
    const float* x   = (const float*)d_in[0];
    const float* emb = (const float*)d_in[1];
    const float* Wp  = (const float*)d_in[2];
    const float* bp  = (const float*)d_in[3];
    const float* W1  = (const float*)d_in[4];
    const float* a1s = (const float*)d_in[5];
    const float* a1d = (const float*)d_in[6];
    const float* b1  = (const float*)d_in[7];
    const float* W2  = (const float*)d_in[8];
    const float* a2s = (const float*)d_in[9];
    const float* a2d = (const float*)d_in[10];
    const float* b2  = (const float*)d_in[11];

    const int ROWS = BATCH * N_NODES;  // 8192

    char* w = (char*)d_ws;
    unsigned short* ne_hi = (unsigned short*)w;  w += (size_t)N_NODES * 64 * 2;
    unsigned short* ne_lo = (unsigned short*)w;  w += (size_t)N_NODES * 64 * 2;
    unsigned long long* mask = (unsigned long long*)w; w += (size_t)N_NODES * 64 * 8;
    float* h1  = (float*)w;                      w += (size_t)ROWS * 64 * 4;
    float* s1s = (float*)w;                      w += (size_t)ROWS * 4 * 4;
    float* s1d = (float*)w;                      w += (size_t)ROWS * 4 * 4;
    float* h2  = (float*)w;                      w += (size_t)ROWS * 32 * 4;
    float* s2s = (float*)w;                      w += (size_t)ROWS * 4 * 4;
    float* s2d = (float*)w;                      w += (size_t)ROWS * 4 * 4;
    int* ecnt  = (int*)w;                        w += (size_t)N_NODES * 4;
    int* elist = (int*)w;                        w += (size_t)N_NODES * EL_CAP * 4;

    k1_kernel<<<dim3(512), dim3(256), 0, stream>>>(
        emb, ne_hi, ne_lo, x, Wp, bp, W1, a1s, a1d, h1, s1s, s1d);
    adj_mfma_kernel<<<dim3(32, 32), dim3(256), 0, stream>>>(ne_hi, ne_lo, mask);
    agg1_fused_kernel<<<dim3(ROWS / 4), dim3(256), 0, stream>>>(
        h1, s1s, s1d, mask, b1, W2, a2s, a2d, h2, s2s, s2d, ecnt, elist);
    agg2_kernel<<<dim3(ROWS / 4), dim3(256), 0, stream>>>(
        h2, s2s, s2d, mask, b2, ecnt, elist, (float*)d_out);
}

// Round 11
// 35.468 us; speedup vs baseline: 5.5535x; 1.1290x over previous
//
#include <hip/hip_runtime.h>
#include <hip/hip_bf16.h>
#include <stdint.h>

#define N_NODES 4096
#define BATCH 2

typedef __attribute__((ext_vector_type(8))) short short8v;
typedef __attribute__((ext_vector_type(4))) unsigned short ushort4v;
typedef __attribute__((ext_vector_type(4))) float f32x4;

#define GLL16(gsrc, ldst) \
    __builtin_amdgcn_global_load_lds((const __attribute__((address_space(1))) void*)(gsrc), \
                                     (__attribute__((address_space(3))) void*)(ldst), 16, 0, 0)

static __device__ inline unsigned short f2bf_rn(float x) {
    unsigned u = __float_as_uint(x);
    unsigned r = (u + 0x7FFFu + ((u >> 16) & 1u)) >> 16;
    return (unsigned short)r;
}
static __device__ inline float bf2f(unsigned short b) {
    return __uint_as_float(((unsigned)b) << 16);
}
static __device__ inline float rl(float v, int k) {   // wave-uniform broadcast
    return __uint_as_float(__builtin_amdgcn_readlane(__float_as_uint(v), k));
}

// ---------------------------------------------------------------------------
// K1 (R5-verified): blocks [0,256) norm -> split-bf16; [256,512) feat1.
// ---------------------------------------------------------------------------
__global__ __launch_bounds__(256) void k1_kernel(
        const float* __restrict__ emb,
        unsigned short* __restrict__ ne_hi, unsigned short* __restrict__ ne_lo,
        const float* __restrict__ x, const float* __restrict__ Wp,
        const float* __restrict__ bp, const float* __restrict__ W1,
        const float* __restrict__ a1s, const float* __restrict__ a1d,
        float* __restrict__ h1out, float* __restrict__ ssrc, float* __restrict__ sdst) {
    int t = threadIdx.x;
    if (blockIdx.x < 256) {
        int row = blockIdx.x * 16 + (t >> 4);
        int l16 = t & 15;
        float4 v = *(const float4*)&emb[(size_t)row * 64 + l16 * 4];
        float s = v.x * v.x + v.y * v.y + v.z * v.z + v.w * v.w;
#pragma unroll
        for (int m = 8; m >= 1; m >>= 1) s += __shfl_xor(s, m);
        float inv = 1.f / sqrtf(s);
        float n0 = v.x * inv, n1 = v.y * inv, n2 = v.z * inv, n3 = v.w * inv;
        ushort4v h = {f2bf_rn(n0), f2bf_rn(n1), f2bf_rn(n2), f2bf_rn(n3)};
        ushort4v lo = {f2bf_rn(n0 - bf2f(h.x)), f2bf_rn(n1 - bf2f(h.y)),
                       f2bf_rn(n2 - bf2f(h.z)), f2bf_rn(n3 - bf2f(h.w))};
        *(ushort4v*)&ne_hi[(size_t)row * 64 + l16 * 4] = h;
        *(ushort4v*)&ne_lo[(size_t)row * 64 + l16 * 4] = lo;
    } else {
        int b = blockIdx.x - 256;
        int w = t >> 6, l = t & 63;
        int row0 = b * 32 + w * 8;

        float xv[8];
#pragma unroll
        for (int r = 0; r < 8; ++r) xv[r] = x[(size_t)(row0 + r) * 16 + (l & 15)];

        float h0[8];
        float bpv = bp[l];
#pragma unroll
        for (int r = 0; r < 8; ++r) h0[r] = bpv;
#pragma unroll
        for (int k = 0; k < 16; ++k) {
            float wk = Wp[k * 64 + l];
#pragma unroll
            for (int r = 0; r < 8; ++r) h0[r] += rl(xv[r], k) * wk;
        }

        float h1[8] = {0.f, 0.f, 0.f, 0.f, 0.f, 0.f, 0.f, 0.f};
#pragma unroll
        for (int k = 0; k < 64; ++k) {
            float wk = W1[k * 64 + l];
#pragma unroll
            for (int r = 0; r < 8; ++r) h1[r] += rl(h0[r], k) * wk;
        }

        float as_ = a1s[l], ad_ = a1d[l];
#pragma unroll
        for (int r = 0; r < 8; ++r) {
            h1out[(size_t)(row0 + r) * 64 + l] = h1[r];
            float ps = h1[r] * as_, pd = h1[r] * ad_;
#pragma unroll
            for (int m = 8; m >= 1; m >>= 1) {
                ps += __shfl_xor(ps, m);
                pd += __shfl_xor(pd, m);
            }
            if ((l & 15) == 0) {
                ssrc[(size_t)(row0 + r) * 4 + (l >> 4)] = ps;
                sdst[(size_t)(row0 + r) * 4 + (l >> 4)] = pd;
            }
        }
    }
}

// ---------------------------------------------------------------------------
// K2 (R5-verified): adjacency bitmask, 128x128 tile/block, LDS-staged MFMA.
// ---------------------------------------------------------------------------
__global__ __launch_bounds__(256) void adj_mfma_kernel(
        const unsigned short* __restrict__ hi, const unsigned short* __restrict__ lo,
        unsigned long long* __restrict__ mask) {
    __shared__ unsigned short Ah[128 * 64];
    __shared__ unsigned short Al[128 * 64];
    __shared__ unsigned short Bh[128 * 64];
    __shared__ unsigned short Bl[128 * 64];
    int t = threadIdx.x;
    int w = t >> 6, l = t & 63;
    int i0 = blockIdx.y * 128, j0 = blockIdx.x * 128;

    int cr = l >> 3;
    int slot = (l & 7) ^ cr;
#pragma unroll
    for (int q = 0; q < 4; ++q) {
        int lr = w * 32 + q * 8;
        size_t ga = (size_t)(i0 + lr + cr) * 64 + slot * 8;
        size_t gb = (size_t)(j0 + lr + cr) * 64 + slot * 8;
        GLL16(hi + ga, &Ah[lr * 64]);
        GLL16(lo + ga, &Al[lr * 64]);
        GLL16(hi + gb, &Bh[lr * 64]);
        GLL16(lo + gb, &Bl[lr * 64]);
    }
    __syncthreads();

    int fr = l & 15;
    int s0 = l >> 4;
    int r7 = l & 7;
    short8v aH[2][2], aL[2][2];
#pragma unroll
    for (int rt = 0; rt < 2; ++rt) {
        int base = (w * 32 + rt * 16 + fr) * 64;
        aH[rt][0] = *(const short8v*)&Ah[base + ((s0 ^ r7) << 3)];
        aH[rt][1] = *(const short8v*)&Ah[base + (((s0 + 4) ^ r7) << 3)];
        aL[rt][0] = *(const short8v*)&Al[base + ((s0 ^ r7) << 3)];
        aL[rt][1] = *(const short8v*)&Al[base + (((s0 + 4) ^ r7) << 3)];
    }

    f32x4 acc[2][8];
#pragma unroll
    for (int rt = 0; rt < 2; ++rt)
#pragma unroll
        for (int js = 0; js < 8; ++js) acc[rt][js] = (f32x4){0.f, 0.f, 0.f, 0.f};

#pragma unroll
    for (int js = 0; js < 8; ++js) {
        int bbase = (js * 16 + fr) * 64;
        short8v bH0 = *(const short8v*)&Bh[bbase + ((s0 ^ r7) << 3)];
        short8v bH1 = *(const short8v*)&Bh[bbase + (((s0 + 4) ^ r7) << 3)];
        short8v bL0 = *(const short8v*)&Bl[bbase + ((s0 ^ r7) << 3)];
        short8v bL1 = *(const short8v*)&Bl[bbase + (((s0 + 4) ^ r7) << 3)];
#pragma unroll
        for (int rt = 0; rt < 2; ++rt) {
            f32x4 a = acc[rt][js];
            a = __builtin_amdgcn_mfma_f32_16x16x32_bf16(aH[rt][0], bH0, a, 0, 0, 0);
            a = __builtin_amdgcn_mfma_f32_16x16x32_bf16(aH[rt][1], bH1, a, 0, 0, 0);
            a = __builtin_amdgcn_mfma_f32_16x16x32_bf16(aH[rt][0], bL0, a, 0, 0, 0);
            a = __builtin_amdgcn_mfma_f32_16x16x32_bf16(aH[rt][1], bL1, a, 0, 0, 0);
            a = __builtin_amdgcn_mfma_f32_16x16x32_bf16(aL[rt][0], bH0, a, 0, 0, 0);
            a = __builtin_amdgcn_mfma_f32_16x16x32_bf16(aL[rt][1], bH1, a, 0, 0, 0);
            acc[rt][js] = a;
        }
    }

    int shift = ((l & 15) >> 2) * 16;
    int r = l & 3;
#pragma unroll
    for (int rt = 0; rt < 2; ++rt) {
#pragma unroll
        for (int ws_ = 0; ws_ < 2; ++ws_) {
            unsigned long long w64 = 0;
#pragma unroll
            for (int js2 = 0; js2 < 4; ++js2) {
                f32x4 a = acc[rt][ws_ * 4 + js2];
                unsigned long long c0 = __ballot(a[0] > 0.5f);
                unsigned long long c1 = __ballot(a[1] > 0.5f);
                unsigned long long c2 = __ballot(a[2] > 0.5f);
                unsigned long long c3 = __ballot(a[3] > 0.5f);
                unsigned long long sel = r == 0 ? c0 : r == 1 ? c1 : r == 2 ? c2 : c3;
                w64 |= ((sel >> shift) & 0xFFFFULL) << (js2 * 16);
            }
            if (l < 16)
                mask[(size_t)(i0 + w * 32 + rt * 16 + l) * 64 + blockIdx.x * 2 + ws_] = w64;
        }
    }
}

// ---------------------------------------------------------------------------
// K3: agg1(+bias+ReLU)+mm2+scores2, BATCH-PAIRED: one wave per node handles
// both batch rows (mask read & edge decode once, 2 softmax states).
// Per-row FP op order identical to R5 -> bit-identical output.
// ---------------------------------------------------------------------------
__global__ __launch_bounds__(256) void agg1_fused_kernel(
        const float* __restrict__ h1, const float* __restrict__ ssrc,
        const float* __restrict__ sdst, const unsigned long long* __restrict__ mask,
        const float* __restrict__ b1, const float* __restrict__ W2,
        const float* __restrict__ a2s, const float* __restrict__ a2d,
        float* __restrict__ h2out, float* __restrict__ s2s, float* __restrict__ s2d) {
    int i = blockIdx.x * 4 + (threadIdx.x >> 6);   // node 0..4095
    int t = threadIdx.x & 63;
    int hh = t >> 4;

    float sdA = sdst[(size_t)i * 4 + hh];
    float sdB = sdst[(size_t)(i + N_NODES) * 4 + hh];
    unsigned long long myword = mask[(size_t)i * 64 + t];

    float mA = -1e30f, dA = 0.f, aA = 0.f;
    float mB = -1e30f, dB = 0.f, aB = 0.f;
    unsigned long long nz = __ballot(myword != 0ULL);
    while (nz) {
        int lw = __ffsll(nz) - 1;
        nz &= nz - 1;
        unsigned long long wbits = __shfl(myword, lw);
        while (wbits) {
            int bpos = __ffsll(wbits) - 1;
            wbits &= wbits - 1;
            int j = (lw << 6) + bpos;
            float ssA = ssrc[(size_t)j * 4 + hh];
            float ssB = ssrc[(size_t)(j + N_NODES) * 4 + hh];
            float hvA = h1[(size_t)j * 64 + t];
            float hvB = h1[(size_t)(j + N_NODES) * 64 + t];
            float e = sdA + ssA;
            e = e > 0.f ? e : 0.2f * e;
            float mn = fmaxf(mA, e);
            float cf = __expf(mA - mn);
            float wg = __expf(e - mn);
            dA = dA * cf + wg;
            aA = aA * cf + wg * hvA;
            mA = mn;
            e = sdB + ssB;
            e = e > 0.f ? e : 0.2f * e;
            mn = fmaxf(mB, e);
            cf = __expf(mB - mn);
            wg = __expf(e - mn);
            dB = dB * cf + wg;
            aB = aB * cf + wg * hvB;
            mB = mn;
        }
    }
    float b1v = b1[t];
    float oA = fmaxf(aA / dA + b1v, 0.f);
    float oB = fmaxf(aB / dB + b1v, 0.f);

    // mm2 for both rows (lanes 32..63 duplicate 0..31)
    int l2 = t & 31;
    float acc2A = 0.f, acc2B = 0.f;
#pragma unroll
    for (int k = 0; k < 64; ++k) {
        float wk = W2[k * 32 + l2];
        acc2A += rl(oA, k) * wk;
        acc2B += rl(oB, k) * wk;
    }

    float a2sv = a2s[l2], a2dv = a2d[l2];
    float psA = acc2A * a2sv, pdA = acc2A * a2dv;
    float psB = acc2B * a2sv, pdB = acc2B * a2dv;
#pragma unroll
    for (int mm = 4; mm >= 1; mm >>= 1) {
        psA += __shfl_xor(psA, mm);
        pdA += __shfl_xor(pdA, mm);
        psB += __shfl_xor(psB, mm);
        pdB += __shfl_xor(pdB, mm);
    }
    if (t < 32) {
        h2out[(size_t)i * 32 + t] = acc2A;
        h2out[(size_t)(i + N_NODES) * 32 + t] = acc2B;
        if ((t & 7) == 0) {
            s2s[(size_t)i * 4 + (t >> 3)] = psA;
            s2d[(size_t)i * 4 + (t >> 3)] = pdA;
            s2s[(size_t)(i + N_NODES) * 4 + (t >> 3)] = psB;
            s2d[(size_t)(i + N_NODES) * 4 + (t >> 3)] = pdB;
        }
    }
}

// ---------------------------------------------------------------------------
// K4: agg2, BATCH-PAIRED -> d_out.
// ---------------------------------------------------------------------------
__global__ __launch_bounds__(256) void agg2_kernel(
        const float* __restrict__ hfeat, const float* __restrict__ ssrc,
        const float* __restrict__ sdst, const unsigned long long* __restrict__ mask,
        const float* __restrict__ bias, float* __restrict__ out) {
    int i = blockIdx.x * 4 + (threadIdx.x >> 6);   // node 0..4095
    int t = threadIdx.x & 63;
    int tt = t & 31;
    int hh = tt >> 3;

    float sdA = sdst[(size_t)i * 4 + hh];
    float sdB = sdst[(size_t)(i + N_NODES) * 4 + hh];
    unsigned long long myword = mask[(size_t)i * 64 + t];

    float mA = -1e30f, dA = 0.f, aA = 0.f;
    float mB = -1e30f, dB = 0.f, aB = 0.f;
    unsigned long long nz = __ballot(myword != 0ULL);
    while (nz) {
        int lw = __ffsll(nz) - 1;
        nz &= nz - 1;
        unsigned long long wbits = __shfl(myword, lw);
        while (wbits) {
            int bpos = __ffsll(wbits) - 1;
            wbits &= wbits - 1;
            int j = (lw << 6) + bpos;
            float ssA = ssrc[(size_t)j * 4 + hh];
            float ssB = ssrc[(size_t)(j + N_NODES) * 4 + hh];
            float hvA = hfeat[(size_t)j * 32 + tt];
            float hvB = hfeat[(size_t)(j + N_NODES) * 32 + tt];
            float e = sdA + ssA;
            e = e > 0.f ? e : 0.2f * e;
            float mn = fmaxf(mA, e);
            float cf = __expf(mA - mn);
            float wg = __expf(e - mn);
            dA = dA * cf + wg;
            aA = aA * cf + wg * hvA;
            mA = mn;
            e = sdB + ssB;
            e = e > 0.f ? e : 0.2f * e;
            mn = fmaxf(mB, e);
            cf = __expf(mB - mn);
            wg = __expf(e - mn);
            dB = dB * cf + wg;
            aB = aB * cf + wg * hvB;
            mB = mn;
        }
    }
    float bv = bias[tt];
    if (t < 32) {
        out[(size_t)i * 32 + tt] = aA / dA + bv;
        out[(size_t)(i + N_NODES) * 32 + tt] = aB / dB + bv;
    }
}

// ---------------------------------------------------------------------------
extern "C" void kernel_launch(void* const* d_in, const int* in_sizes, int n_in,
                              void* d_out, int out_size, void* d_ws, size_t ws_size,
                              hipStream_t stream) {
    const float* x   = (const float*)d_in[0];
    const float* emb = (const float*)d_in[1];
    const float* Wp  = (const float*)d_in[2];
    const float* bp  = (const float*)d_in[3];
    const float* W1  = (const float*)d_in[4];
    const float* a1s = (const float*)d_in[5];
    const float* a1d = (const float*)d_in[6];
    const float* b1  = (const float*)d_in[7];
    const float* W2  = (const float*)d_in[8];
    const float* a2s = (const float*)d_in[9];
    const float* a2d = (const float*)d_in[10];
    const float* b2  = (const float*)d_in[11];

    const int ROWS = BATCH * N_NODES;  // 8192

    char* w = (char*)d_ws;
    unsigned short* ne_hi = (unsigned short*)w;  w += (size_t)N_NODES * 64 * 2;
    unsigned short* ne_lo = (unsigned short*)w;  w += (size_t)N_NODES * 64 * 2;
    unsigned long long* mask = (unsigned long long*)w; w += (size_t)N_NODES * 64 * 8;
    float* h1  = (float*)w;                      w += (size_t)ROWS * 64 * 4;
    float* s1s = (float*)w;                      w += (size_t)ROWS * 4 * 4;
    float* s1d = (float*)w;                      w += (size_t)ROWS * 4 * 4;
    float* h2  = (float*)w;                      w += (size_t)ROWS * 32 * 4;
    float* s2s = (float*)w;                      w += (size_t)ROWS * 4 * 4;
    float* s2d = (float*)w;                      w += (size_t)ROWS * 4 * 4;

    k1_kernel<<<dim3(512), dim3(256), 0, stream>>>(
        emb, ne_hi, ne_lo, x, Wp, bp, W1, a1s, a1d, h1, s1s, s1d);
    adj_mfma_kernel<<<dim3(32, 32), dim3(256), 0, stream>>>(ne_hi, ne_lo, mask);
    agg1_fused_kernel<<<dim3(N_NODES / 4), dim3(256), 0, stream>>>(
        h1, s1s, s1d, mask, b1, W2, a2s, a2d, h2, s2s, s2d);
    agg2_kernel<<<dim3(N_NODES / 4), dim3(256), 0, stream>>>(
        h2, s2s, s2d, mask, b2, (float*)d_out);
}

// Round 12
// 33.658 us; speedup vs baseline: 5.8522x; 1.0538x over previous
//
#include <hip/hip_runtime.h>
#include <hip/hip_bf16.h>
#include <stdint.h>

#define N_NODES 4096
#define BATCH 2

typedef __attribute__((ext_vector_type(8))) short short8v;
typedef __attribute__((ext_vector_type(4))) unsigned short ushort4v;
typedef __attribute__((ext_vector_type(4))) float f32x4;

#define GLL16(gsrc, ldst) \
    __builtin_amdgcn_global_load_lds((const __attribute__((address_space(1))) void*)(gsrc), \
                                     (__attribute__((address_space(3))) void*)(ldst), 16, 0, 0)

static __device__ inline unsigned short f2bf_rn(float x) {
    unsigned u = __float_as_uint(x);
    unsigned r = (u + 0x7FFFu + ((u >> 16) & 1u)) >> 16;
    return (unsigned short)r;
}
static __device__ inline float bf2f(unsigned short b) {
    return __uint_as_float(((unsigned)b) << 16);
}
static __device__ inline float rl(float v, int k) {   // wave-uniform broadcast
    return __uint_as_float(__builtin_amdgcn_readlane(__float_as_uint(v), k));
}

// ---------------------------------------------------------------------------
// K1: norm only -> split-bf16 ne (adj's sole prerequisite). 16 rows/block.
// ---------------------------------------------------------------------------
__global__ __launch_bounds__(256) void norm_kernel(
        const float* __restrict__ emb,
        unsigned short* __restrict__ ne_hi, unsigned short* __restrict__ ne_lo) {
    int t = threadIdx.x;
    int row = blockIdx.x * 16 + (t >> 4);
    int l16 = t & 15;
    float4 v = *(const float4*)&emb[(size_t)row * 64 + l16 * 4];
    float s = v.x * v.x + v.y * v.y + v.z * v.z + v.w * v.w;
#pragma unroll
    for (int m = 8; m >= 1; m >>= 1) s += __shfl_xor(s, m);
    float inv = 1.f / sqrtf(s);
    float n0 = v.x * inv, n1 = v.y * inv, n2 = v.z * inv, n3 = v.w * inv;
    ushort4v h = {f2bf_rn(n0), f2bf_rn(n1), f2bf_rn(n2), f2bf_rn(n3)};
    ushort4v lo = {f2bf_rn(n0 - bf2f(h.x)), f2bf_rn(n1 - bf2f(h.y)),
                   f2bf_rn(n2 - bf2f(h.z)), f2bf_rn(n3 - bf2f(h.w))};
    *(ushort4v*)&ne_hi[(size_t)row * 64 + l16 * 4] = h;
    *(ushort4v*)&ne_lo[(size_t)row * 64 + l16 * 4] = lo;
}

// ---------------------------------------------------------------------------
// K2 fat kernel: blocks [0,256) feat1 (independent of norm);
//                blocks [256,1280) adjacency, BK=32 two-step, 32 KiB LDS.
// LDS[row][s] = global[row][s ^ (row&3)] (4-slot XOR swizzle, 16B slots);
// fragment read at slot s0^(fr&3) -> max 2-way bank aliasing (free).
// ---------------------------------------------------------------------------
__global__ __launch_bounds__(256) void k2_kernel(
        const unsigned short* __restrict__ hi, const unsigned short* __restrict__ lo,
        unsigned long long* __restrict__ mask,
        const float* __restrict__ x, const float* __restrict__ Wp,
        const float* __restrict__ bp, const float* __restrict__ W1,
        const float* __restrict__ a1s, const float* __restrict__ a1d,
        float* __restrict__ h1out, float* __restrict__ ssrc, float* __restrict__ sdst) {
    __shared__ unsigned short Ah[128 * 32];
    __shared__ unsigned short Al[128 * 32];
    __shared__ unsigned short Bh[128 * 32];
    __shared__ unsigned short Bl[128 * 32];
    int t = threadIdx.x;
    int w = t >> 6, l = t & 63;

    if (blockIdx.x < 256) {
        // ================= feat1: proj + mm1 + scores1 (R5-verified) =======
        int b = blockIdx.x;
        int row0 = b * 32 + w * 8;

        float xv[8];
#pragma unroll
        for (int r = 0; r < 8; ++r) xv[r] = x[(size_t)(row0 + r) * 16 + (l & 15)];

        float h0[8];
        float bpv = bp[l];
#pragma unroll
        for (int r = 0; r < 8; ++r) h0[r] = bpv;
#pragma unroll
        for (int k = 0; k < 16; ++k) {
            float wk = Wp[k * 64 + l];
#pragma unroll
            for (int r = 0; r < 8; ++r) h0[r] += rl(xv[r], k) * wk;
        }

        float h1[8] = {0.f, 0.f, 0.f, 0.f, 0.f, 0.f, 0.f, 0.f};
#pragma unroll
        for (int k = 0; k < 64; ++k) {
            float wk = W1[k * 64 + l];
#pragma unroll
            for (int r = 0; r < 8; ++r) h1[r] += rl(h0[r], k) * wk;
        }

        float as_ = a1s[l], ad_ = a1d[l];
#pragma unroll
        for (int r = 0; r < 8; ++r) {
            h1out[(size_t)(row0 + r) * 64 + l] = h1[r];
            float ps = h1[r] * as_, pd = h1[r] * ad_;
#pragma unroll
            for (int m = 8; m >= 1; m >>= 1) {
                ps += __shfl_xor(ps, m);
                pd += __shfl_xor(pd, m);
            }
            if ((l & 15) == 0) {
                ssrc[(size_t)(row0 + r) * 4 + (l >> 4)] = ps;
                sdst[(size_t)(row0 + r) * 4 + (l >> 4)] = pd;
            }
        }
        return;
    }

    // ================= adjacency =================
    int tile = blockIdx.x - 256;
    int bi = tile >> 5, bj = tile & 31;
    int i0 = bi * 128, j0 = bj * 128;

    int fr = l & 15;
    int s0 = l >> 4;                     // logical 16B slot 0..3 (k = s0*8)
    int sw = (s0 ^ (fr & 3)) << 3;       // swizzled slot offset (shorts)

    f32x4 acc[2][8];
#pragma unroll
    for (int rt = 0; rt < 2; ++rt)
#pragma unroll
        for (int js = 0; js < 8; ++js) acc[rt][js] = (f32x4){0.f, 0.f, 0.f, 0.f};

    int cr = l >> 2;                     // staging: row within 16-row chunk
    int sl = (l & 3) ^ (cr & 3);         // pre-swizzled source slot

#pragma unroll 1
    for (int ks = 0; ks < 2; ++ks) {
        // ---- stage k-half ks: wave w rows [w*32, w*32+32), 2 chunks ----
#pragma unroll
        for (int q = 0; q < 2; ++q) {
            int lr = w * 32 + q * 16;
            size_t ga = (size_t)(i0 + lr + cr) * 64 + ks * 32 + sl * 8;
            size_t gb = (size_t)(j0 + lr + cr) * 64 + ks * 32 + sl * 8;
            GLL16(hi + ga, &Ah[lr * 32]);
            GLL16(lo + ga, &Al[lr * 32]);
            GLL16(hi + gb, &Bh[lr * 32]);
            GLL16(lo + gb, &Bl[lr * 32]);
        }
        __syncthreads();

        short8v aH[2], aL[2];
#pragma unroll
        for (int rt = 0; rt < 2; ++rt) {
            int base = (w * 32 + rt * 16 + fr) * 32 + sw;
            aH[rt] = *(const short8v*)&Ah[base];
            aL[rt] = *(const short8v*)&Al[base];
        }

#pragma unroll
        for (int js = 0; js < 8; ++js) {
            int bbase = (js * 16 + fr) * 32 + sw;
            short8v bH = *(const short8v*)&Bh[bbase];
            short8v bL = *(const short8v*)&Bl[bbase];
#pragma unroll
            for (int rt = 0; rt < 2; ++rt) {
                f32x4 a = acc[rt][js];
                a = __builtin_amdgcn_mfma_f32_16x16x32_bf16(aH[rt], bH, a, 0, 0, 0);
                a = __builtin_amdgcn_mfma_f32_16x16x32_bf16(aH[rt], bL, a, 0, 0, 0);
                a = __builtin_amdgcn_mfma_f32_16x16x32_bf16(aL[rt], bH, a, 0, 0, 0);
                acc[rt][js] = a;
            }
        }
        if (ks == 0) __syncthreads();   // LDS reuse guard before restage
    }

    // ---- pack to bitmask. C/D layout: col=lane&15, row=(lane>>4)*4+reg ----
    int shift = ((l & 15) >> 2) * 16;
    int r = l & 3;
#pragma unroll
    for (int rt = 0; rt < 2; ++rt) {
#pragma unroll
        for (int ws_ = 0; ws_ < 2; ++ws_) {
            unsigned long long w64 = 0;
#pragma unroll
            for (int js2 = 0; js2 < 4; ++js2) {
                f32x4 a = acc[rt][ws_ * 4 + js2];
                unsigned long long c0 = __ballot(a[0] > 0.5f);
                unsigned long long c1 = __ballot(a[1] > 0.5f);
                unsigned long long c2 = __ballot(a[2] > 0.5f);
                unsigned long long c3 = __ballot(a[3] > 0.5f);
                unsigned long long sel = r == 0 ? c0 : r == 1 ? c1 : r == 2 ? c2 : c3;
                w64 |= ((sel >> shift) & 0xFFFFULL) << (js2 * 16);
            }
            if (l < 16)
                mask[(size_t)(i0 + w * 32 + rt * 16 + l) * 64 + bj * 2 + ws_] = w64;
        }
    }
}

// ---------------------------------------------------------------------------
// K3 (R11-verified): agg1(+bias+ReLU)+mm2+scores2, batch-paired.
// ---------------------------------------------------------------------------
__global__ __launch_bounds__(256) void agg1_fused_kernel(
        const float* __restrict__ h1, const float* __restrict__ ssrc,
        const float* __restrict__ sdst, const unsigned long long* __restrict__ mask,
        const float* __restrict__ b1, const float* __restrict__ W2,
        const float* __restrict__ a2s, const float* __restrict__ a2d,
        float* __restrict__ h2out, float* __restrict__ s2s, float* __restrict__ s2d) {
    int i = blockIdx.x * 4 + (threadIdx.x >> 6);   // node 0..4095
    int t = threadIdx.x & 63;
    int hh = t >> 4;

    float sdA = sdst[(size_t)i * 4 + hh];
    float sdB = sdst[(size_t)(i + N_NODES) * 4 + hh];
    unsigned long long myword = mask[(size_t)i * 64 + t];

    float mA = -1e30f, dA = 0.f, aA = 0.f;
    float mB = -1e30f, dB = 0.f, aB = 0.f;
    unsigned long long nz = __ballot(myword != 0ULL);
    while (nz) {
        int lw = __ffsll(nz) - 1;
        nz &= nz - 1;
        unsigned long long wbits = __shfl(myword, lw);
        while (wbits) {
            int bpos = __ffsll(wbits) - 1;
            wbits &= wbits - 1;
            int j = (lw << 6) + bpos;
            float ssA = ssrc[(size_t)j * 4 + hh];
            float ssB = ssrc[(size_t)(j + N_NODES) * 4 + hh];
            float hvA = h1[(size_t)j * 64 + t];
            float hvB = h1[(size_t)(j + N_NODES) * 64 + t];
            float e = sdA + ssA;
            e = e > 0.f ? e : 0.2f * e;
            float mn = fmaxf(mA, e);
            float cf = __expf(mA - mn);
            float wg = __expf(e - mn);
            dA = dA * cf + wg;
            aA = aA * cf + wg * hvA;
            mA = mn;
            e = sdB + ssB;
            e = e > 0.f ? e : 0.2f * e;
            mn = fmaxf(mB, e);
            cf = __expf(mB - mn);
            wg = __expf(e - mn);
            dB = dB * cf + wg;
            aB = aB * cf + wg * hvB;
            mB = mn;
        }
    }
    float b1v = b1[t];
    float oA = fmaxf(aA / dA + b1v, 0.f);
    float oB = fmaxf(aB / dB + b1v, 0.f);

    // mm2 for both rows (lanes 32..63 duplicate 0..31)
    int l2 = t & 31;
    float acc2A = 0.f, acc2B = 0.f;
#pragma unroll
    for (int k = 0; k < 64; ++k) {
        float wk = W2[k * 32 + l2];
        acc2A += rl(oA, k) * wk;
        acc2B += rl(oB, k) * wk;
    }

    float a2sv = a2s[l2], a2dv = a2d[l2];
    float psA = acc2A * a2sv, pdA = acc2A * a2dv;
    float psB = acc2B * a2sv, pdB = acc2B * a2dv;
#pragma unroll
    for (int mm = 4; mm >= 1; mm >>= 1) {
        psA += __shfl_xor(psA, mm);
        pdA += __shfl_xor(pdA, mm);
        psB += __shfl_xor(psB, mm);
        pdB += __shfl_xor(pdB, mm);
    }
    if (t < 32) {
        h2out[(size_t)i * 32 + t] = acc2A;
        h2out[(size_t)(i + N_NODES) * 32 + t] = acc2B;
        if ((t & 7) == 0) {
            s2s[(size_t)i * 4 + (t >> 3)] = psA;
            s2d[(size_t)i * 4 + (t >> 3)] = pdA;
            s2s[(size_t)(i + N_NODES) * 4 + (t >> 3)] = psB;
            s2d[(size_t)(i + N_NODES) * 4 + (t >> 3)] = pdB;
        }
    }
}

// ---------------------------------------------------------------------------
// K4 (R11-verified): agg2, batch-paired -> d_out.
// ---------------------------------------------------------------------------
__global__ __launch_bounds__(256) void agg2_kernel(
        const float* __restrict__ hfeat, const float* __restrict__ ssrc,
        const float* __restrict__ sdst, const unsigned long long* __restrict__ mask,
        const float* __restrict__ bias, float* __restrict__ out) {
    int i = blockIdx.x * 4 + (threadIdx.x >> 6);   // node 0..4095
    int t = threadIdx.x & 63;
    int tt = t & 31;
    int hh = tt >> 3;

    float sdA = sdst[(size_t)i * 4 + hh];
    float sdB = sdst[(size_t)(i + N_NODES) * 4 + hh];
    unsigned long long myword = mask[(size_t)i * 64 + t];

    float mA = -1e30f, dA = 0.f, aA = 0.f;
    float mB = -1e30f, dB = 0.f, aB = 0.f;
    unsigned long long nz = __ballot(myword != 0ULL);
    while (nz) {
        int lw = __ffsll(nz) - 1;
        nz &= nz - 1;
        unsigned long long wbits = __shfl(myword, lw);
        while (wbits) {
            int bpos = __ffsll(wbits) - 1;
            wbits &= wbits - 1;
            int j = (lw << 6) + bpos;
            float ssA = ssrc[(size_t)j * 4 + hh];
            float ssB = ssrc[(size_t)(j + N_NODES) * 4 + hh];
            float hvA = hfeat[(size_t)j * 32 + tt];
            float hvB = hfeat[(size_t)(j + N_NODES) * 32 + tt];
            float e = sdA + ssA;
            e = e > 0.f ? e : 0.2f * e;
            float mn = fmaxf(mA, e);
            float cf = __expf(mA - mn);
            float wg = __expf(e - mn);
            dA = dA * cf + wg;
            aA = aA * cf + wg * hvA;
            mA = mn;
            e = sdB + ssB;
            e = e > 0.f ? e : 0.2f * e;
            mn = fmaxf(mB, e);
            cf = __expf(mB - mn);
            wg = __expf(e - mn);
            dB = dB * cf + wg;
            aB = aB * cf + wg * hvB;
            mB = mn;
        }
    }
    float bv = bias[tt];
    if (t < 32) {
        out[(size_t)i * 32 + tt] = aA / dA + bv;
        out[(size_t)(i + N_NODES) * 32 + tt] = aB / dB + bv;
    }
}

// ---------------------------------------------------------------------------
extern "C" void kernel_launch(void* const* d_in, const int* in_sizes, int n_in,
                              void* d_out, int out_size, void* d_ws, size_t ws_size,
                              hipStream_t stream) {
    const float* x   = (const float*)d_in[0];
    const float* emb = (const float*)d_in[1];
    const float* Wp  = (const float*)d_in[2];
    const float* bp  = (const float*)d_in[3];
    const float* W1  = (const float*)d_in[4];
    const float* a1s = (const float*)d_in[5];
    const float* a1d = (const float*)d_in[6];
    const float* b1  = (const float*)d_in[7];
    const float* W2  = (const float*)d_in[8];
    const float* a2s = (const float*)d_in[9];
    const float* a2d = (const float*)d_in[10];
    const float* b2  = (const float*)d_in[11];

    const int ROWS = BATCH * N_NODES;  // 8192

    char* w = (char*)d_ws;
    unsigned short* ne_hi = (unsigned short*)w;  w += (size_t)N_NODES * 64 * 2;
    unsigned short* ne_lo = (unsigned short*)w;  w += (size_t)N_NODES * 64 * 2;
    unsigned long long* mask = (unsigned long long*)w; w += (size_t)N_NODES * 64 * 8;
    float* h1  = (float*)w;                      w += (size_t)ROWS * 64 * 4;
    float* s1s = (float*)w;                      w += (size_t)ROWS * 4 * 4;
    float* s1d = (float*)w;                      w += (size_t)ROWS * 4 * 4;
    float* h2  = (float*)w;                      w += (size_t)ROWS * 32 * 4;
    float* s2s = (float*)w;                      w += (size_t)ROWS * 4 * 4;
    float* s2d = (float*)w;                      w += (size_t)ROWS * 4 * 4;

    norm_kernel<<<dim3(256), dim3(256), 0, stream>>>(emb, ne_hi, ne_lo);
    k2_kernel<<<dim3(1280), dim3(256), 0, stream>>>(
        ne_hi, ne_lo, mask, x, Wp, bp, W1, a1s, a1d, h1, s1s, s1d);
    agg1_fused_kernel<<<dim3(N_NODES / 4), dim3(256), 0, stream>>>(
        h1, s1s, s1d, mask, b1, W2, a2s, a2d, h2, s2s, s2d);
    agg2_kernel<<<dim3(N_NODES / 4), dim3(256), 0, stream>>>(
        h2, s2s, s2d, mask, b2, (float*)d_out);
}